// Round 4
// baseline (366.184 us; speedup 1.0000x reference)
//
#include <hip/hip_runtime.h>
#include <hip/hip_bf16.h>

// NTXentLoss, B=8192, D=128, temperature=0.1, idx=0.
// Inputs (per reference setup_inputs + harness contract): zis/zjs/weights are
// FLOAT32 (R3 post-mortem: reading them as bf16 produced NaN; the "(bf16,...)"
// label in the harness error is hard-coded and carries no dtype info), labels
// and idx are int32. Output: one float32 scalar (R2->R3 delta proved d_out is
// read as fp32).
//
// Math: loss_i = M + log(exp(pos_i-M) + sum_{j: ilab[j]!=jlab[i]} exp(l_ij-M)) - pos_i
// with FIXED M=10 (valid since l_ij = cos/0.1 <= 10); logsumexp is
// shift-invariant, so identical to the reference's per-row-max shift.

#define BB 8192
#define DD 128
#define TI 64
#define TJ 64
#define KH 64   // k-half width (two-stage K keeps LDS at ~33 KB < 64 KB limit)

static __device__ __forceinline__ float wave_sum(float v) {
#pragma unroll
    for (int off = 32; off > 0; off >>= 1) v += __shfl_xor(v, off, 64);
    return v;
}

// One wave per row. Rows [0,BB) -> zis/rni, [BB,2BB) -> zjs/rnj.
__global__ __launch_bounds__(256) void rnorm_kernel(
    const float* __restrict__ zis, const float* __restrict__ zjs,
    float* __restrict__ rni, float* __restrict__ rnj)
{
    int wave = threadIdx.x >> 6;
    int lane = threadIdx.x & 63;
    int row  = blockIdx.x * 4 + wave;
    const float* src = (row < BB) ? zis : zjs;
    float* dst = (row < BB) ? rni : rnj;
    int r = (row < BB) ? row : (row - BB);
    float2 u = *(const float2*)(src + (size_t)r * DD + lane * 2);
    float s = wave_sum(u.x * u.x + u.y * u.y);
    if (lane == 0) dst[r] = 1.0f / sqrtf(s);
}

// pos[i] = 10 * rnj[i]*rni[idx+i] * dot(zjs[i], zis[idx+i]); one wave per row.
__global__ __launch_bounds__(256) void pos_kernel(
    const float* __restrict__ zis, const float* __restrict__ zjs,
    const float* __restrict__ rni, const float* __restrict__ rnj,
    const int* __restrict__ idxp, float* __restrict__ pos)
{
    int wave = threadIdx.x >> 6;
    int lane = threadIdx.x & 63;
    int i = blockIdx.x * 4 + wave;
    int j = idxp[0] + i;
    float2 a = *(const float2*)(zjs + (size_t)i * DD + lane * 2);
    float2 b = *(const float2*)(zis + (size_t)j * DD + lane * 2);
    float s = wave_sum(a.x * b.x + a.y * b.y);
    if (lane == 0) pos[i] = s * rni[j] * rnj[i] * 10.0f;
}

// 64x64 logits tile per block; fp32 FMA over LDS-staged normalized rows.
// LDS layout: transposed [k][row], stride 64, column XOR-swizzled by
// ((k>>2)&7)<<2 -> conflict-free float4 reads, ~2-way (free) stores.
// K staged in two 64-wide halves.
__global__ __launch_bounds__(256) void tile_kernel(
    const float* __restrict__ zis, const float* __restrict__ zjs,
    const float* __restrict__ rni, const float* __restrict__ rnj,
    const int* __restrict__ ilab, const int* __restrict__ jlab,
    float* __restrict__ denom)
{
    __shared__ float AjT[KH][TI];   // zj rows (i dim), transposed, one k-half
    __shared__ float BiT[KH][TJ];   // zi rows (j dim), transposed, one k-half
    __shared__ int   il[TJ];
    __shared__ int   jl[TI];
    __shared__ float rowsum[TI];

    int tid = threadIdx.x;
    int i0 = blockIdx.y * TI;
    int j0 = blockIdx.x * TJ;

    if (tid < TJ)                   il[tid] = ilab[j0 + tid];
    if (tid >= 64 && tid < 128)     jl[tid - 64] = jlab[i0 + tid - 64];
    if (tid >= 128 && tid < 192)    rowsum[tid - 128] = 0.0f;

    int tx = tid & 15, ty = tid >> 4;
    int isub = ty * 4, jsub = tx * 4;
    float acc[4][4] = {};

    // Staging map: k-quad = 4*(tid&15) within half, row = (tid>>4) + 16*it.
    int ks   = (tid & 15) * 4;
    int row0 = tid >> 4;
    int sw   = (tid & 7) << 2;      // == ((ks>>2)&7)<<2

#pragma unroll
    for (int kh = 0; kh < 2; ++kh) {
        if (kh) __syncthreads();
        int gk = kh * KH + ks;
#pragma unroll
        for (int it = 0; it < 4; ++it) {
            int r  = row0 + it * 16;
            int rs = r ^ sw;
            float4 ua = *(const float4*)(zjs + (size_t)(i0 + r) * DD + gk);
            float sa = rnj[i0 + r];
            AjT[ks + 0][rs] = ua.x * sa;
            AjT[ks + 1][rs] = ua.y * sa;
            AjT[ks + 2][rs] = ua.z * sa;
            AjT[ks + 3][rs] = ua.w * sa;
            float4 ub = *(const float4*)(zis + (size_t)(j0 + r) * DD + gk);
            float sb = rni[j0 + r];
            BiT[ks + 0][rs] = ub.x * sb;
            BiT[ks + 1][rs] = ub.y * sb;
            BiT[ks + 2][rs] = ub.z * sb;
            BiT[ks + 3][rs] = ub.w * sb;
        }
        __syncthreads();

#pragma unroll 4
        for (int kk = 0; kk < KH; ++kk) {
            int swr = ((kk >> 2) & 7) << 2;
            float4 a = *(const float4*)&AjT[kk][isub ^ swr];
            float4 b = *(const float4*)&BiT[kk][jsub ^ swr];
            float av[4] = {a.x, a.y, a.z, a.w};
            float bv[4] = {b.x, b.y, b.z, b.w};
#pragma unroll
            for (int r = 0; r < 4; ++r)
#pragma unroll
                for (int c = 0; c < 4; ++c)
                    acc[r][c] += av[r] * bv[c];
        }
    }

    // Epilogue: masked exp-sum per row (fixed shift M=10).
#pragma unroll
    for (int r = 0; r < 4; ++r) {
        int lr = jl[isub + r];
        float s = 0.0f;
#pragma unroll
        for (int c = 0; c < 4; ++c) {
            float e = __expf(acc[r][c] * 10.0f - 10.0f);
            if (il[jsub + c] != lr) s += e;
        }
        atomicAdd(&rowsum[isub + r], s);
    }
    __syncthreads();
    if (tid < TI) atomicAdd(&denom[i0 + tid], rowsum[tid]);
}

// Single block: loss_i = 10 + log(exp(pos-10)+denom) - pos; *w/w; mean.
// Output float32.
__global__ __launch_bounds__(1024) void final_kernel(
    const float* __restrict__ pos, const float* __restrict__ denom,
    const float* __restrict__ wts, const int* __restrict__ idxp,
    float* __restrict__ out)
{
    int tid = threadIdx.x;
    int idx = idxp[0];
    float s = 0.0f;
    for (int i = tid; i < BB; i += 1024) {
        float p = pos[i];
        float l = 10.0f + logf(__expf(p - 10.0f) + denom[i]) - p;
        float w = wts[idx + i];
        l = (l * w) / w;   // faithful to reference's weighted-sum/weight-sum
        s += l;
    }
    s = wave_sum(s);
    __shared__ float part[16];
    int lane = tid & 63, wv = tid >> 6;
    if (lane == 0) part[wv] = s;
    __syncthreads();
    if (tid == 0) {
        float t = 0.0f;
#pragma unroll
        for (int q = 0; q < 16; ++q) t += part[q];
        out[0] = t * (1.0f / (float)BB);
    }
}

extern "C" void kernel_launch(void* const* d_in, const int* in_sizes, int n_in,
                              void* d_out, int out_size, void* d_ws, size_t ws_size,
                              hipStream_t stream) {
    const float* zis = (const float*)d_in[0];
    const float* zjs = (const float*)d_in[1];
    const int* ilab = (const int*)d_in[2];
    const int* jlab = (const int*)d_in[3];
    const float* wts = (const float*)d_in[4];
    const int* idxp = (const int*)d_in[5];
    float* out = (float*)d_out;

    float* rni   = (float*)d_ws;          // BB floats
    float* rnj   = rni + BB;              // BB floats
    float* pos   = rnj + BB;              // BB floats
    float* denom = pos + BB;              // BB floats

    hipMemsetAsync(denom, 0, BB * sizeof(float), stream);

    rnorm_kernel<<<2 * BB / 4, 256, 0, stream>>>(zis, zjs, rni, rnj);
    pos_kernel<<<BB / 4, 256, 0, stream>>>(zis, zjs, rni, rnj, idxp, pos);
    tile_kernel<<<dim3(BB / TJ, BB / TI), 256, 0, stream>>>(
        zis, zjs, rni, rnj, ilab, jlab, denom);
    final_kernel<<<1, 1024, 0, stream>>>(pos, denom, wts, idxp, out);
}

// Round 5
// 134.742 us; speedup vs baseline: 2.7177x; 2.7177x over previous
//
#include <hip/hip_runtime.h>

// NTXentLoss, B=8192, D=128, T=0.1, idx=0.
// R4: fp32 VALU path PASSED (absmax 0.0, 366 us; tile_kernel 343 us,
// VALUBusy 55%, MfmaUtil 0). fp32-vector structural floor is ~110 us
// (17.2 GF / 157 TF) -> switch the big matmul to bf16 MFMA (threshold is
// 2% relative = 0.1875; bf16-rounded normalized vectors give worst-case
// ~0.04 loss error; pos stays fp32-exact).
//
// Pipeline:
//   prep:  normalize rows (fp32) -> bf16 matrices Zjb (A), Zib (B) in ws,
//          plus 1/norm vectors for the fp32-exact pos kernel.
//   mfma:  128x128 logits tile/block, K=128 in two 64-wide LDS phases
//          (2x16 KB, global_load_lds width=16, XOR-swizzled lane->kq mapping
//          so MFMA-side ds_read_b128 is at most 2-way = free), 4 waves x
//          4x4 16x16x32 acc tiles; fused exp/mask/row-sum epilogue
//          (C/D layout: col=lane&15, row=quad*4+reg -- m89-verified).
//   pos/final: unchanged fp32.
// Fallback to the R4 fp32 path if ws_size can't hold the bf16 copies.

#define BB 8192
#define DD 128
#define TM 128
#define TN 128

typedef __attribute__((ext_vector_type(8))) short short8;
typedef __attribute__((ext_vector_type(4))) float floatx4;

#define GLOBAL_AS __attribute__((address_space(1)))
#define LDS_AS    __attribute__((address_space(3)))

static __device__ __forceinline__ float wave_sum(float v) {
#pragma unroll
    for (int off = 32; off > 0; off >>= 1) v += __shfl_xor(v, off, 64);
    return v;
}

static __device__ __forceinline__ unsigned short f2bf(float f) {
    unsigned int u = __float_as_uint(f);
    return (unsigned short)((u + 0x7FFFu + ((u >> 16) & 1u)) >> 16);
}

// ---- main path: prep (normalize + bf16 convert) --------------------------
// rows [0,BB) -> zis->Zib + rni ; [BB,2BB) -> zjs->Zjb + rnj. One wave/row.
__global__ __launch_bounds__(256) void prep_kernel(
    const float* __restrict__ zis, const float* __restrict__ zjs,
    unsigned short* __restrict__ Zib, unsigned short* __restrict__ Zjb,
    float* __restrict__ rni, float* __restrict__ rnj)
{
    int wave = threadIdx.x >> 6, lane = threadIdx.x & 63;
    int row = blockIdx.x * 4 + wave;
    const float* src; unsigned short* dst; float* rn; int r;
    if (row < BB) { src = zis; dst = Zib; rn = rni; r = row; }
    else          { src = zjs; dst = Zjb; rn = rnj; r = row - BB; }
    float2 u = *(const float2*)(src + (size_t)r * DD + lane * 2);
    float s = wave_sum(u.x * u.x + u.y * u.y);
    float sc = 1.0f / sqrtf(s);
    if (lane == 0) rn[r] = sc;
    ushort2 o; o.x = f2bf(u.x * sc); o.y = f2bf(u.y * sc);
    *(ushort2*)(dst + (size_t)r * DD + lane * 2) = o;
}

// ---- main path: 128x128 MFMA tile ---------------------------------------
__global__ __launch_bounds__(256) void mfma_tile_kernel(
    const unsigned short* __restrict__ Zjb,   // A: zj normalized, [BB][DD]
    const unsigned short* __restrict__ Zib,   // B: zi normalized, [BB][DD]
    const int* __restrict__ ilab, const int* __restrict__ jlab,
    float* __restrict__ denom)
{
    __shared__ unsigned short At[TM * 64];    // one 64-k phase, swizzled
    __shared__ unsigned short Bt[TN * 64];
    __shared__ int   il[TN];
    __shared__ int   jl[TM];
    __shared__ float rowsum[TM];

    int tid  = threadIdx.x;
    int lane = tid & 63, wave = tid >> 6;
    int wm = wave >> 1, wn = wave & 1;        // 2x2 wave grid, 64x64 each
    int quad = lane >> 4, l15 = lane & 15;
    int i0 = blockIdx.y * TM, j0 = blockIdx.x * TN;

    if (tid < TN) { il[tid] = ilab[j0 + tid]; rowsum[tid] = 0.0f; }
    else          { jl[tid - 128] = jlab[i0 + tid - 128]; }

    floatx4 acc[4][4];
#pragma unroll
    for (int a = 0; a < 4; ++a)
#pragma unroll
        for (int b = 0; b < 4; ++b) acc[a][b] = (floatx4){0.f, 0.f, 0.f, 0.f};

    // staging lane map: 1 KB region = 8 rows x 64 k bf16; lane l handles
    // row r*8 + (l>>3), kq = (l&7) ^ (l>>3)  (XOR swizzle embedded in the
    // global address so the wave-uniform-base LDS write lands swizzled).
    int srow8 = lane >> 3;
    int kq_l  = (lane & 7) ^ srow8;

#pragma unroll
    for (int ph = 0; ph < 2; ++ph) {
        if (ph) __syncthreads();              // LDS reuse fence
#pragma unroll
        for (int g = wave; g < 32; g += 4) {  // 16 A-regions + 16 B-regions
            int rg = g & 15;
            int rowl = rg * 8 + srow8;
            const unsigned short* gp = (g < 16)
                ? (Zjb + (size_t)(i0 + rowl) * DD + ph * 64 + kq_l * 8)
                : (Zib + (size_t)(j0 + rowl) * DD + ph * 64 + kq_l * 8);
            unsigned short* lp = ((g < 16) ? At : Bt) + rg * 512;  // wave-uniform
            __builtin_amdgcn_global_load_lds((const GLOBAL_AS void*)gp,
                                             (LDS_AS void*)lp, 16, 0, 0);
        }
        __syncthreads();                      // drains vmcnt before barrier

#pragma unroll
        for (int kc = 0; kc < 2; ++kc) {      // two 32-k MFMA chunks per phase
            int kq = kc * 4 + quad;
            short8 af[4], bfr[4];
#pragma unroll
            for (int t = 0; t < 4; ++t) {
                int m = wm * 64 + t * 16 + l15;
                af[t]  = *(const short8*)&At[m * 64 + ((kq ^ (m & 7)) << 3)];
                int n = wn * 64 + t * 16 + l15;
                bfr[t] = *(const short8*)&Bt[n * 64 + ((kq ^ (n & 7)) << 3)];
            }
#pragma unroll
            for (int mt = 0; mt < 4; ++mt)
#pragma unroll
                for (int nt = 0; nt < 4; ++nt)
                    acc[mt][nt] = __builtin_amdgcn_mfma_f32_16x16x32_bf16(
                        af[mt], bfr[nt], acc[mt][nt], 0, 0, 0);
        }
    }

    // epilogue: logit = 10*c; e = exp(logit-10); mask il[col]!=jl[row]; rowsum
#pragma unroll
    for (int mt = 0; mt < 4; ++mt) {
#pragma unroll
        for (int r = 0; r < 4; ++r) {
            int rowl = wm * 64 + mt * 16 + quad * 4 + r;
            int jr = jl[rowl];
            float s = 0.0f;
#pragma unroll
            for (int nt = 0; nt < 4; ++nt) {
                int col = wn * 64 + nt * 16 + l15;
                float e = __expf(fmaf(acc[mt][nt][r], 10.0f, -10.0f));
                s += (il[col] != jr) ? e : 0.0f;
            }
            s += __shfl_xor(s, 1, 64);
            s += __shfl_xor(s, 2, 64);
            s += __shfl_xor(s, 4, 64);
            s += __shfl_xor(s, 8, 64);
            if (l15 == 0) atomicAdd(&rowsum[rowl], s);
        }
    }
    __syncthreads();
    if (tid < TM) atomicAdd(&denom[i0 + tid], rowsum[tid]);
}

// ---- pos (fp32-exact) ----------------------------------------------------
__global__ __launch_bounds__(256) void pos_kernel(
    const float* __restrict__ zis, const float* __restrict__ zjs,
    const float* __restrict__ rni, const float* __restrict__ rnj,
    const int* __restrict__ idxp, float* __restrict__ pos)
{
    int wave = threadIdx.x >> 6, lane = threadIdx.x & 63;
    int i = blockIdx.x * 4 + wave;
    int j = idxp[0] + i;
    float2 a = *(const float2*)(zjs + (size_t)i * DD + lane * 2);
    float2 b = *(const float2*)(zis + (size_t)j * DD + lane * 2);
    float s = wave_sum(a.x * b.x + a.y * b.y);
    if (lane == 0) pos[i] = s * rni[j] * rnj[i] * 10.0f;
}

// ---- finalize ------------------------------------------------------------
__global__ __launch_bounds__(1024) void final_kernel(
    const float* __restrict__ pos, const float* __restrict__ denom,
    const float* __restrict__ wts, const int* __restrict__ idxp,
    float* __restrict__ out)
{
    int tid = threadIdx.x;
    int idx = idxp[0];
    float s = 0.0f;
    for (int i = tid; i < BB; i += 1024) {
        float p = pos[i];
        float l = 10.0f + logf(__expf(p - 10.0f) + denom[i]) - p;
        float w = wts[idx + i];
        l = (l * w) / w;
        s += l;
    }
    s = wave_sum(s);
    __shared__ float part[16];
    int lane = tid & 63, wv = tid >> 6;
    if (lane == 0) part[wv] = s;
    __syncthreads();
    if (tid == 0) {
        float t = 0.0f;
#pragma unroll
        for (int q = 0; q < 16; ++q) t += part[q];
        out[0] = t * (1.0f / (float)BB);
    }
}

// ---- fallback path (R4, fp32 VALU) --------------------------------------
#define TI 64
#define TJ 64
#define KH 64
__global__ __launch_bounds__(256) void rnorm_kernel(
    const float* __restrict__ zis, const float* __restrict__ zjs,
    float* __restrict__ rni, float* __restrict__ rnj)
{
    int wave = threadIdx.x >> 6, lane = threadIdx.x & 63;
    int row = blockIdx.x * 4 + wave;
    const float* src = (row < BB) ? zis : zjs;
    float* dst = (row < BB) ? rni : rnj;
    int r = (row < BB) ? row : (row - BB);
    float2 u = *(const float2*)(src + (size_t)r * DD + lane * 2);
    float s = wave_sum(u.x * u.x + u.y * u.y);
    if (lane == 0) dst[r] = 1.0f / sqrtf(s);
}

__global__ __launch_bounds__(256) void tile_kernel(
    const float* __restrict__ zis, const float* __restrict__ zjs,
    const float* __restrict__ rni, const float* __restrict__ rnj,
    const int* __restrict__ ilab, const int* __restrict__ jlab,
    float* __restrict__ denom)
{
    __shared__ float AjT[KH][TI];
    __shared__ float BiT[KH][TJ];
    __shared__ int   il[TJ];
    __shared__ int   jl[TI];
    __shared__ float rowsum[TI];

    int tid = threadIdx.x;
    int i0 = blockIdx.y * TI, j0 = blockIdx.x * TJ;
    if (tid < TJ)               il[tid] = ilab[j0 + tid];
    if (tid >= 64 && tid < 128) jl[tid - 64] = jlab[i0 + tid - 64];
    if (tid >= 128 && tid < 192) rowsum[tid - 128] = 0.0f;

    int tx = tid & 15, ty = tid >> 4;
    int isub = ty * 4, jsub = tx * 4;
    float acc[4][4] = {};
    int ks = (tid & 15) * 4, row0 = tid >> 4, sw = (tid & 7) << 2;

#pragma unroll
    for (int kh = 0; kh < 2; ++kh) {
        if (kh) __syncthreads();
        int gk = kh * KH + ks;
#pragma unroll
        for (int it = 0; it < 4; ++it) {
            int r = row0 + it * 16, rs = r ^ sw;
            float4 ua = *(const float4*)(zjs + (size_t)(i0 + r) * DD + gk);
            float sa = rnj[i0 + r];
            AjT[ks + 0][rs] = ua.x * sa; AjT[ks + 1][rs] = ua.y * sa;
            AjT[ks + 2][rs] = ua.z * sa; AjT[ks + 3][rs] = ua.w * sa;
            float4 ub = *(const float4*)(zis + (size_t)(j0 + r) * DD + gk);
            float sb = rni[j0 + r];
            BiT[ks + 0][rs] = ub.x * sb; BiT[ks + 1][rs] = ub.y * sb;
            BiT[ks + 2][rs] = ub.z * sb; BiT[ks + 3][rs] = ub.w * sb;
        }
        __syncthreads();
#pragma unroll 4
        for (int kk = 0; kk < KH; ++kk) {
            int swr = ((kk >> 2) & 7) << 2;
            float4 a = *(const float4*)&AjT[kk][isub ^ swr];
            float4 b = *(const float4*)&BiT[kk][jsub ^ swr];
            float av[4] = {a.x, a.y, a.z, a.w};
            float bv[4] = {b.x, b.y, b.z, b.w};
#pragma unroll
            for (int r = 0; r < 4; ++r)
#pragma unroll
                for (int c = 0; c < 4; ++c) acc[r][c] += av[r] * bv[c];
        }
    }
#pragma unroll
    for (int r = 0; r < 4; ++r) {
        int lr = jl[isub + r];
        float s = 0.0f;
#pragma unroll
        for (int c = 0; c < 4; ++c) {
            float e = __expf(acc[r][c] * 10.0f - 10.0f);
            if (il[jsub + c] != lr) s += e;
        }
        atomicAdd(&rowsum[isub + r], s);
    }
    __syncthreads();
    if (tid < TI) atomicAdd(&denom[i0 + tid], rowsum[tid]);
}

// ---- launch --------------------------------------------------------------
extern "C" void kernel_launch(void* const* d_in, const int* in_sizes, int n_in,
                              void* d_out, int out_size, void* d_ws, size_t ws_size,
                              hipStream_t stream) {
    const float* zis = (const float*)d_in[0];
    const float* zjs = (const float*)d_in[1];
    const int* ilab = (const int*)d_in[2];
    const int* jlab = (const int*)d_in[3];
    const float* wts = (const float*)d_in[4];
    const int* idxp = (const int*)d_in[5];
    float* out = (float*)d_out;

    float* rni   = (float*)d_ws;
    float* rnj   = rni + BB;
    float* pos   = rnj + BB;
    float* denom = pos + BB;
    unsigned short* Zib = (unsigned short*)(denom + BB);  // [BB][DD] bf16
    unsigned short* Zjb = Zib + (size_t)BB * DD;          // [BB][DD] bf16

    size_t need = 4u * BB * sizeof(float) + 2u * (size_t)BB * DD * sizeof(unsigned short);

    hipMemsetAsync(denom, 0, BB * sizeof(float), stream);

    if (ws_size >= need) {
        prep_kernel<<<2 * BB / 4, 256, 0, stream>>>(zis, zjs, Zib, Zjb, rni, rnj);
        pos_kernel<<<BB / 4, 256, 0, stream>>>(zis, zjs, rni, rnj, idxp, pos);
        mfma_tile_kernel<<<dim3(BB / TN, BB / TM), 256, 0, stream>>>(
            Zjb, Zib, ilab, jlab, denom);
    } else {
        rnorm_kernel<<<2 * BB / 4, 256, 0, stream>>>(zis, zjs, rni, rnj);
        pos_kernel<<<BB / 4, 256, 0, stream>>>(zis, zjs, rni, rnj, idxp, pos);
        tile_kernel<<<dim3(BB / TJ, BB / TI), 256, 0, stream>>>(
            zis, zjs, rni, rnj, ilab, jlab, denom);
    }
    final_kernel<<<1, 1024, 0, stream>>>(pos, denom, wts, idxp, out);
}

// Round 6
// 131.765 us; speedup vs baseline: 2.7791x; 1.0226x over previous
//
#include <hip/hip_runtime.h>

// NTXentLoss, B=8192, D=128, T=0.1, idx=0. fp32 in, fp32 scalar out.
// R5: MFMA path passed, tile 59.7 us but MfmaUtil 10.6%/VALUBusy 35% ->
// latency-bound (2 monolithic K-phases, full barrier drain each).
// R6: 4-phase K=32 ping-pong pipeline (loads for ph+1 in flight during
// compute of ph), swizzle rebalanced for 64-B row stride (2-way max = free);
// pos fused into multi-block final.

#define BB 8192
#define DD 128
#define TM 128
#define TN 128
#define KP 32
#define NPH 4

typedef __attribute__((ext_vector_type(8))) short short8;
typedef __attribute__((ext_vector_type(4))) float floatx4;

#define GLOBAL_AS __attribute__((address_space(1)))
#define LDS_AS    __attribute__((address_space(3)))

static __device__ __forceinline__ float wave_sum(float v) {
#pragma unroll
    for (int off = 32; off > 0; off >>= 1) v += __shfl_xor(v, off, 64);
    return v;
}

static __device__ __forceinline__ unsigned short f2bf(float f) {
    unsigned int u = __float_as_uint(f);
    return (unsigned short)((u + 0x7FFFu + ((u >> 16) & 1u)) >> 16);
}

// ---- prep: normalize rows (fp32) -> bf16 copies + 1/norm ----------------
__global__ __launch_bounds__(256) void prep_kernel(
    const float* __restrict__ zis, const float* __restrict__ zjs,
    unsigned short* __restrict__ Zib, unsigned short* __restrict__ Zjb,
    float* __restrict__ rni, float* __restrict__ rnj)
{
    int wave = threadIdx.x >> 6, lane = threadIdx.x & 63;
    int row = blockIdx.x * 4 + wave;
    const float* src; unsigned short* dst; float* rn; int r;
    if (row < BB) { src = zis; dst = Zib; rn = rni; r = row; }
    else          { src = zjs; dst = Zjb; rn = rnj; r = row - BB; }
    float2 u = *(const float2*)(src + (size_t)r * DD + lane * 2);
    float s = wave_sum(u.x * u.x + u.y * u.y);
    float sc = 1.0f / sqrtf(s);
    if (lane == 0) rn[r] = sc;
    ushort2 o; o.x = f2bf(u.x * sc); o.y = f2bf(u.y * sc);
    *(ushort2*)(dst + (size_t)r * DD + lane * 2) = o;
}

// ---- 128x128 MFMA tile, 4-phase K=32 ping-pong pipeline ------------------
// Swizzle (row stride 32 bf16 = 64 B = 16 banks): k-slot = q ^ ((m^(m>>2))&3)
// -> each (row-parity, slot) class holds exactly 2 of 16 rows => 2-way = free.
__global__ __launch_bounds__(256) void mfma_tile_kernel(
    const unsigned short* __restrict__ Zjb,   // A: zj normalized
    const unsigned short* __restrict__ Zib,   // B: zi normalized
    const int* __restrict__ ilab, const int* __restrict__ jlab,
    float* __restrict__ denom)
{
    __shared__ __align__(16) unsigned short At[2][TM * KP];  // 8 KB per buf
    __shared__ __align__(16) unsigned short Bt[2][TN * KP];
    __shared__ int   il[TN];
    __shared__ int   jl[TM];
    __shared__ float rowsum[TM];

    int tid  = threadIdx.x;
    int lane = tid & 63, wave = tid >> 6;
    int wm = wave >> 1, wn = wave & 1;        // 2x2 wave grid, 64x64 each
    int quad = lane >> 4, l15 = lane & 15;
    int i0 = blockIdx.y * TM, j0 = blockIdx.x * TN;

    if (tid < TN) { il[tid] = ilab[j0 + tid]; rowsum[tid] = 0.0f; }
    else          { jl[tid - 128] = jlab[i0 + tid - 128]; }

    floatx4 acc[4][4];
#pragma unroll
    for (int a = 0; a < 4; ++a)
#pragma unroll
        for (int b = 0; b < 4; ++b) acc[a][b] = (floatx4){0.f, 0.f, 0.f, 0.f};

    const unsigned short* srcA = Zjb + (size_t)i0 * DD;
    const unsigned short* srcB = Zib + (size_t)j0 * DD;

    // staging: 16 regions of 1 KB (16 rows x 32 k); lane l -> row l>>2,
    // k-slot (l&3)^swz(row), written to LDS base + l*16 (HW scatter).
    int r_in    = lane >> 2;
    int slot_st = lane & 3;

    auto stage = [&](int ph, int buf) {
#pragma unroll
        for (int t = 0; t < 4; ++t) {
            int g = wave + t * 4;                 // 0..15
            int isA = (g < 8) ? 1 : 0;
            int rbase = (isA ? g : g - 8) * 16;
            int grow = rbase + r_in;
            int slot = slot_st ^ ((grow ^ (grow >> 2)) & 3);
            const unsigned short* gp = (isA ? srcA : srcB)
                + (size_t)grow * DD + ph * KP + slot * 8;
            unsigned short* lp = isA ? &At[buf][rbase * KP]
                                     : &Bt[buf][rbase * KP];
            __builtin_amdgcn_global_load_lds((const GLOBAL_AS void*)gp,
                                             (LDS_AS void*)lp, 16, 0, 0);
        }
    };

    auto compute = [&](int buf) {
        short8 af[4], bfr[4];
#pragma unroll
        for (int t = 0; t < 4; ++t) {
            int m = wm * 64 + t * 16 + l15;
            int sA = quad ^ ((m ^ (m >> 2)) & 3);
            af[t] = *(const short8*)&At[buf][m * KP + sA * 8];
            int n = wn * 64 + t * 16 + l15;
            int sB = quad ^ ((n ^ (n >> 2)) & 3);
            bfr[t] = *(const short8*)&Bt[buf][n * KP + sB * 8];
        }
#pragma unroll
        for (int mt = 0; mt < 4; ++mt)
#pragma unroll
            for (int nt = 0; nt < 4; ++nt)
                acc[mt][nt] = __builtin_amdgcn_mfma_f32_16x16x32_bf16(
                    af[mt], bfr[nt], acc[mt][nt], 0, 0, 0);
    };

    stage(0, 0);
    __syncthreads();                 // phase-0 staging landed (+ il/jl/rowsum)
#pragma unroll
    for (int ph = 0; ph < NPH; ++ph) {
        if (ph + 1 < NPH) stage(ph + 1, (ph + 1) & 1);  // prefetch, in flight
        compute(ph & 1);                                 // overlaps prefetch
        __syncthreads();             // drains prefetch; fences buffer reuse
    }

    // epilogue: e = exp(10*c-10), mask, row-sum (C/D: col=l15, row=quad*4+r)
#pragma unroll
    for (int mt = 0; mt < 4; ++mt) {
#pragma unroll
        for (int r = 0; r < 4; ++r) {
            int rowl = wm * 64 + mt * 16 + quad * 4 + r;
            int jr = jl[rowl];
            float s = 0.0f;
#pragma unroll
            for (int nt = 0; nt < 4; ++nt) {
                int col = wn * 64 + nt * 16 + l15;
                float e = __expf(fmaf(acc[mt][nt][r], 10.0f, -10.0f));
                s += (il[col] != jr) ? e : 0.0f;
            }
            s += __shfl_xor(s, 1, 64);
            s += __shfl_xor(s, 2, 64);
            s += __shfl_xor(s, 4, 64);
            s += __shfl_xor(s, 8, 64);
            if (l15 == 0) atomicAdd(&rowsum[rowl], s);
        }
    }
    __syncthreads();
    if (tid < TM) atomicAdd(&denom[i0 + tid], rowsum[tid]);
}

// ---- fused pos + finalize (512 blocks, 4 rows/wave, 1 atomic/block) ------
__global__ __launch_bounds__(256) void posfinal_kernel(
    const float* __restrict__ zis, const float* __restrict__ zjs,
    const float* __restrict__ rni, const float* __restrict__ rnj,
    const float* __restrict__ denom, const float* __restrict__ wts,
    const int* __restrict__ idxp, float* __restrict__ out)
{
    int wave = threadIdx.x >> 6, lane = threadIdx.x & 63;
    int idx = idxp[0];
    float ll = 0.0f;
#pragma unroll
    for (int t = 0; t < 4; ++t) {
        int i = blockIdx.x * 16 + wave * 4 + t;
        int j = idx + i;
        float2 a  = *(const float2*)(zjs + (size_t)i * DD + lane * 2);
        float2 b2 = *(const float2*)(zis + (size_t)j * DD + lane * 2);
        float s = wave_sum(a.x * b2.x + a.y * b2.y);
        if (lane == 0) {
            float p = s * rni[j] * rnj[i] * 10.0f;
            float l = 10.0f + logf(__expf(p - 10.0f) + denom[i]) - p;
            float w = wts[j];
            ll += (l * w) / w;    // faithful to reference's weighted mean
        }
    }
    __shared__ float part[4];
    if (lane == 0) part[wave] = ll;
    __syncthreads();
    if (threadIdx.x == 0)
        atomicAdd(out, (part[0] + part[1] + part[2] + part[3]) * (1.0f / BB));
}

// ---- launch --------------------------------------------------------------
extern "C" void kernel_launch(void* const* d_in, const int* in_sizes, int n_in,
                              void* d_out, int out_size, void* d_ws, size_t ws_size,
                              hipStream_t stream) {
    const float* zis = (const float*)d_in[0];
    const float* zjs = (const float*)d_in[1];
    const int* ilab = (const int*)d_in[2];
    const int* jlab = (const int*)d_in[3];
    const float* wts = (const float*)d_in[4];
    const int* idxp = (const int*)d_in[5];
    float* out = (float*)d_out;

    float* rni   = (float*)d_ws;
    float* rnj   = rni + BB;
    float* denom = rnj + BB;
    unsigned short* Zib = (unsigned short*)(denom + BB);  // [BB][DD] bf16
    unsigned short* Zjb = Zib + (size_t)BB * DD;

    hipMemsetAsync(denom, 0, BB * sizeof(float), stream);
    hipMemsetAsync(out, 0, out_size * sizeof(float), stream);  // d_ws/d_out poisoned 0xAA

    prep_kernel<<<2 * BB / 4, 256, 0, stream>>>(zis, zjs, Zib, Zjb, rni, rnj);
    mfma_tile_kernel<<<dim3(BB / TN, BB / TM), 256, 0, stream>>>(
        Zjb, Zib, ilab, jlab, denom);
    posfinal_kernel<<<BB / 16, 256, 0, stream>>>(
        zis, zjs, rni, rnj, denom, wts, idxp, out);
}